// Round 18
// baseline (123.467 us; speedup 1.0000x reference)
//
#include <hip/hip_runtime.h>
#include <hip/hip_bf16.h>

#define DM 1024
#define SD 32
#define NG 8
#define GD 128
#define BS 4
#define TT 4096
#define CL 64        // chunk length
#define NC (TT/CL)   // 64 chunks
#define NCHAIN (BS*NG)

typedef __attribute__((ext_vector_type(8))) short short8;
typedef __attribute__((ext_vector_type(4))) float f32x4;

// workspace
#define WS_CARRY 0                          // f32[NCHAIN][NC][SD] = 256KB
#define WS_FLG   (NCHAIN*NC*SD*4)           // u32[NCHAIN][NC] = 8KB (zeroed per call)

__device__ __forceinline__ unsigned short f2bf(float f) {
  __hip_bfloat16 h = __float2bfloat16(f);
  return __builtin_bit_cast(unsigned short, h);
}
__device__ __forceinline__ float bf2f(unsigned short h) {
  return __uint_as_float(((unsigned)h) << 16);
}
__device__ __forceinline__ float softplus_f(float x) {
  return (x > 20.f) ? x : log1pf(expf(x));
}
__device__ __forceinline__ short8 pack8(float4 a, float4 b) {
  short8 h;
  h[0]=(short)f2bf(a.x); h[1]=(short)f2bf(a.y); h[2]=(short)f2bf(a.z); h[3]=(short)f2bf(a.w);
  h[4]=(short)f2bf(b.x); h[5]=(short)f2bf(b.y); h[6]=(short)f2bf(b.z); h[7]=(short)f2bf(b.w);
  return h;
}

// ---- fused: Bu GEMM + scan (states in LDS) + carry publish + PARALLEL poll + prefix + C GEMM + y ----
__global__ __launch_bounds__(64, 2) void fused_s5(const float* __restrict__ u,
                                                  const float* __restrict__ state0,
                                                  const float* __restrict__ A_log,
                                                  const float* __restrict__ B_param,
                                                  const float* __restrict__ C,
                                                  const float* __restrict__ Dp,
                                                  const float* __restrict__ dt_logit,
                                                  unsigned char* __restrict__ ws,
                                                  float* __restrict__ y,
                                                  float* __restrict__ sfin) {
  const int bx = blockIdx.x;
  const int c = bx & (NC - 1);
  const int g = (bx >> 6) & (NG - 1);
  const int b = bx >> 9;
  const int chain = b * NG + g;
  const int l = threadIdx.x;
  const int lr = l & 15, lh = l >> 4;
  const int n = l & 31;

  float* carry = (float*)(ws + WS_CARRY);
  unsigned* flg = (unsigned*)(ws + WS_FLG);

  __shared__ __align__(16) float sBu[CL * 33];            // 8448B
  __shared__ __align__(16) unsigned short sSt[CL * SD];   // 4096B (live into phase B)

  const float dtg = 0.001f + 0.099f * (1.f / (1.f + expf(-dt_logit[g])));

  // per-lane-n decay (all 64 lanes; lanes 32-63 duplicate n)
  const float l2a_n = -softplus_f(A_log[g * SD + n]) * dtg * 1.44269504f;
  const float a_n = exp2f(l2a_n);

  float fracv[2];
  #pragma unroll
  for (int nt = 0; nt < 2; ++nt) {
    int np = nt * 16 + lr;
    float A = -softplus_f(A_log[g * SD + np]);
    float a = expf(A * dtg);
    fracv[nt] = (fabsf(A) > 1e-6f) ? (a - 1.f) / A : dtg;
  }

  // B fragments
  const float* bp = B_param + (size_t)g * SD * GD;
  short8 bfr[4][2];
  #pragma unroll
  for (int kt = 0; kt < 4; ++kt)
    #pragma unroll
    for (int nt = 0; nt < 2; ++nt) {
      const float* p = bp + (size_t)(nt * 16 + lr) * GD + kt * 32 + lh * 8;
      float4 v0 = *(const float4*)p;
      float4 v1 = *(const float4*)(p + 4);
      float s = fracv[nt];
      v0.x*=s; v0.y*=s; v0.z*=s; v0.w*=s;
      v1.x*=s; v1.y*=s; v1.z*=s; v1.w*=s;
      bfr[kt][nt] = pack8(v0, v1);
    }

  // ---- phase A GEMM (2-deep u pipeline, R11-proven) ----
  const float* up = u + ((size_t)b * TT + (size_t)c * CL) * DM + g * GD;
  float4 ub[2][4][2];
  #pragma unroll
  for (int kt = 0; kt < 2; ++kt)
    #pragma unroll
    for (int m = 0; m < 4; ++m) {
      const float* p = up + (size_t)(m * 16 + lr) * DM + kt * 32 + lh * 8;
      ub[kt][m][0] = *(const float4*)p;
      ub[kt][m][1] = *(const float4*)(p + 4);
    }

  f32x4 acc[4][2];
  #pragma unroll
  for (int m = 0; m < 4; ++m)
    #pragma unroll
    for (int nt = 0; nt < 2; ++nt)
      #pragma unroll
      for (int j = 0; j < 4; ++j) acc[m][nt][j] = 0.f;

  #pragma unroll
  for (int kt = 0; kt < 4; ++kt) {
    short8 af[4];
    #pragma unroll
    for (int m = 0; m < 4; ++m)
      af[m] = pack8(ub[kt & 1][m][0], ub[kt & 1][m][1]);
    if (kt < 2) {
      #pragma unroll
      for (int m = 0; m < 4; ++m) {
        const float* p = up + (size_t)(m * 16 + lr) * DM + (kt + 2) * 32 + lh * 8;
        ub[kt & 1][m][0] = *(const float4*)p;
        ub[kt & 1][m][1] = *(const float4*)(p + 4);
      }
    }
    #pragma unroll
    for (int m = 0; m < 4; ++m)
      #pragma unroll
      for (int nt = 0; nt < 2; ++nt)
        acc[m][nt] = __builtin_amdgcn_mfma_f32_16x16x32_bf16(af[m], bfr[kt][nt], acc[m][nt], 0, 0, 0);
  }

  #pragma unroll
  for (int m = 0; m < 4; ++m)
    #pragma unroll
    for (int nt = 0; nt < 2; ++nt)
      #pragma unroll
      for (int j = 0; j < 4; ++j) {
        int t = m * 16 + lh * 4 + j;   // C/D: row=(lane>>4)*4+j, col=lane&15
        sBu[t * 33 + (nt * 16 + lr)] = acc[m][nt][j];
      }
  __syncthreads();

  // ---- local scan (zero entry); states stay in LDS; publish carry ----
  float s_agg = 0.f;
  if (l < SD) {
    float s = 0.f;
    #pragma unroll
    for (int t = 0; t < CL; ++t) {
      s = fmaf(s, a_n, sBu[t * 33 + l]);
      sSt[t * SD + l] = f2bf(s);
    }
    s_agg = s;
    __hip_atomic_store(&carry[(chain * NC + c) * SD + l], s,
                       __ATOMIC_RELAXED, __HIP_MEMORY_SCOPE_AGENT);
  }
  __builtin_amdgcn_fence(__ATOMIC_RELEASE, "agent");
  if (l == 0)
    __hip_atomic_store(&flg[chain * NC + c], 1u,
                       __ATOMIC_RELEASE, __HIP_MEMORY_SCOPE_AGENT);

  // ---- PARALLEL poll: all predecessor flags checked in ONE vector load per sweep ----
  if (c > 0) {
    const unsigned* f = flg + chain * NC;
    while (true) {
      unsigned v = (l < c) ? __hip_atomic_load(&f[l], __ATOMIC_RELAXED,
                                               __HIP_MEMORY_SCOPE_AGENT) : 1u;
      if (__all(v != 0)) break;
      __builtin_amdgcn_s_sleep(4);
    }
  }
  __builtin_amdgcn_fence(__ATOMIC_ACQUIRE, "agent");

  // ---- chunk-entry prefix: p = state0*aL^c + sum_j aL^(c-1-j)*carry_j (fixed order) ----
  float p;
  {
    const float k64 = 64.f * l2a_n;
    const float* ap = carry + (size_t)chain * NC * SD + n;
    float a0 = 0.f, a1 = 0.f, a2 = 0.f, a3 = 0.f;
    int j = 0;
    for (; j + 4 <= c; j += 4) {
      float w0 = exp2f((float)(c - 1 - j) * k64);
      float w1 = exp2f((float)(c - 2 - j) * k64);
      float w2 = exp2f((float)(c - 3 - j) * k64);
      float w3 = exp2f((float)(c - 4 - j) * k64);
      a0 = fmaf(w0, ap[(size_t)(j + 0) * SD], a0);
      a1 = fmaf(w1, ap[(size_t)(j + 1) * SD], a1);
      a2 = fmaf(w2, ap[(size_t)(j + 2) * SD], a2);
      a3 = fmaf(w3, ap[(size_t)(j + 3) * SD], a3);
    }
    for (; j < c; ++j)
      a0 = fmaf(exp2f((float)(c - 1 - j) * k64), ap[(size_t)j * SD], a0);
    p = fmaf(state0[chain * SD + n], exp2f((float)c * k64),
             (a0 + a1) + (a2 + a3));
    if (c == NC - 1 && l < SD)
      sfin[chain * SD + l] = fmaf(p, exp2f(k64), s_agg);
  }

  // broadcast pref + decay across the wave
  float pr[8], l2av[8];
  #pragma unroll
  for (int e = 0; e < 8; ++e) {
    pr[e]   = __shfl(p, lh * 8 + e);
    l2av[e] = __shfl(l2a_n, lh * 8 + e);
  }

  // ---- corrected state fragments (B operand: col=t, k=n) ----
  short8 sf[4];
  #pragma unroll
  for (int tt = 0; tt < 4; ++tt) {
    int t = tt * 16 + lr;
    short8 sl = *(const short8*)(sSt + t * SD + lh * 8);
    short8 hh;
    #pragma unroll
    for (int e = 0; e < 8; ++e) {
      float w = exp2f((float)(t + 1) * l2av[e]);
      hh[e] = (short)f2bf(fmaf(w, pr[e], bf2f((unsigned short)sl[e])));
    }
    sf[tt] = hh;
  }

  // Dp==0 detection: skip the u re-read in the epilogue
  bool need_u;
  {
    float2 dpc = *(const float2*)(Dp + g * GD + l * 2);
    need_u = __ballot((dpc.x != 0.f) || (dpc.y != 0.f)) != 0ULL;
  }

  // ---- C GEMM (swapped): D[d][t] = sum_n C[d][n]*s[t][n]; float4 epilogue ----
  const float* cp = C + (size_t)g * GD * SD;
  const size_t rowbase = ((size_t)b * TT + (size_t)c * CL) * DM + g * GD;

  #pragma unroll
  for (int h = 0; h < 2; ++h) {
    short8 cf[4];
    #pragma unroll
    for (int dd = 0; dd < 4; ++dd) {
      int d = (h * 4 + dd) * 16 + lr;
      const float* pp = cp + (size_t)d * SD + lh * 8;
      float4 v0 = *(const float4*)pp;
      float4 v1 = *(const float4*)(pp + 4);
      cf[dd] = pack8(v0, v1);
    }
    f32x4 acc2[4][4];
    #pragma unroll
    for (int dd = 0; dd < 4; ++dd)
      #pragma unroll
      for (int tt = 0; tt < 4; ++tt) {
        f32x4 z;
        #pragma unroll
        for (int j = 0; j < 4; ++j) z[j] = 0.f;
        acc2[dd][tt] = __builtin_amdgcn_mfma_f32_16x16x32_bf16(cf[dd], sf[tt], z, 0, 0, 0);
      }
    #pragma unroll
    for (int dd = 0; dd < 4; ++dd) {
      int d0 = (h * 4 + dd) * 16 + lh * 4;
      float4 dp4 = *(const float4*)(Dp + g * GD + d0);
      #pragma unroll
      for (int tt = 0; tt < 4; ++tt) {
        int t = tt * 16 + lr;
        size_t off = rowbase + (size_t)t * DM + d0;
        float4 r;
        r.x = acc2[dd][tt][0]; r.y = acc2[dd][tt][1];
        r.z = acc2[dd][tt][2]; r.w = acc2[dd][tt][3];
        if (need_u) {
          float4 u4 = *(const float4*)(u + off);
          r.x += dp4.x * u4.x; r.y += dp4.y * u4.y;
          r.z += dp4.z * u4.z; r.w += dp4.w * u4.w;
        }
        *(float4*)(y + off) = r;
      }
    }
  }
}

extern "C" void kernel_launch(void* const* d_in, const int* in_sizes, int n_in,
                              void* d_out, int out_size, void* d_ws, size_t ws_size,
                              hipStream_t stream) {
  const float* u       = (const float*)d_in[0];
  const float* state0  = (const float*)d_in[1];
  const float* A_log   = (const float*)d_in[2];
  const float* B_param = (const float*)d_in[3];
  const float* C       = (const float*)d_in[4];
  const float* Dp      = (const float*)d_in[5];
  const float* dtl     = (const float*)d_in[6];
  float* y = (float*)d_out;
  unsigned char* ws = (unsigned char*)d_ws;
  float* sfin = y + (size_t)BS * TT * DM;

  hipMemsetAsync(ws + WS_FLG, 0, NCHAIN * NC * sizeof(unsigned), stream);
  fused_s5<<<dim3(BS * NG * NC), dim3(64), 0, stream>>>(u, state0, A_log, B_param, C, Dp, dtl, ws, y, sfin);
}

// Round 19
// 40.940 us; speedup vs baseline: 3.0158x; 3.0158x over previous
//
#include <hip/hip_runtime.h>
#include <hip/hip_bf16.h>

#define DM 1024
#define SD 32
#define NG 8
#define GD 128
#define BS 4
#define TT 4096
#define CL 64        // chunk length
#define NC (TT/CL)   // 64 chunks

typedef __attribute__((ext_vector_type(8))) short short8;
typedef __attribute__((ext_vector_type(4))) float f32x4;

// workspace layout (bytes), 16B aligned
#define WS_POWA  0                         // f32[8][64][32]  = 64KB  (powA[g][t][n] = Abar^(t+1))
#define WS_STL   65536                     // bf16[4][64][8][64][32] = 8MB (local-scan states)
#define WS_CARRY (WS_STL + 8388608)        // f32[4][8][64][32] = 256KB, layout [b][g][c][n]
#define WS_PAL   (WS_CARRY + 262144)       // f32[8][64][32] = 64KB (powAL[g][j][n] = (a^64)^j)

__device__ __forceinline__ unsigned short f2bf(float f) {
  __hip_bfloat16 h = __float2bfloat16(f);
  return __builtin_bit_cast(unsigned short, h);
}
__device__ __forceinline__ float bf2f(unsigned short h) {
  return __uint_as_float(((unsigned)h) << 16);
}
__device__ __forceinline__ float softplus_f(float x) {
  return (x > 20.f) ? x : log1pf(expf(x));
}
__device__ __forceinline__ short8 pack8(float4 a, float4 b) {
  short8 h;
  h[0]=(short)f2bf(a.x); h[1]=(short)f2bf(a.y); h[2]=(short)f2bf(a.z); h[3]=(short)f2bf(a.w);
  h[4]=(short)f2bf(b.x); h[5]=(short)f2bf(b.y); h[6]=(short)f2bf(b.z); h[7]=(short)f2bf(b.w);
  return h;
}

// ---------------- KA: reg-pipelined Bu GEMM + local scan (R11; g-fastest dispatch) ----------------
__global__ __launch_bounds__(64) void ka_bu_scan(const float* __restrict__ u,
                                                 const float* __restrict__ A_log,
                                                 const float* __restrict__ B_param,
                                                 const float* __restrict__ dt_logit,
                                                 unsigned char* __restrict__ ws) {
  const int bx = blockIdx.x;
  // DISPATCH REMAP: g fastest -> the 8 blocks sharing (b,c) are adjacent in dispatch,
  // so their 512B slices of each 4KB u row arrive at DRAM together (full-row bursts).
  const int g = bx & (NG - 1);
  const int c = (bx >> 3) & (NC - 1);
  const int b = bx >> 9;
  const int l = threadIdx.x;
  const int lr = l & 15, lh = l >> 4;

  const float dtg = 0.001f + 0.099f * (1.f / (1.f + expf(-dt_logit[g])));

  float fracv[2];
  #pragma unroll
  for (int nt = 0; nt < 2; ++nt) {
    int n = nt * 16 + lr;
    float A = -softplus_f(A_log[g * SD + n]);
    float a = expf(A * dtg);
    fracv[nt] = (fabsf(A) > 1e-6f) ? (a - 1.f) / A : dtg;
  }
  float a_scan;
  {
    float A = -softplus_f(A_log[g * SD + (l & 31)]);
    a_scan = expf(A * dtg);
  }

  const float* bp = B_param + (size_t)g * SD * GD;
  short8 bfr[4][2];
  #pragma unroll
  for (int kt = 0; kt < 4; ++kt)
    #pragma unroll
    for (int nt = 0; nt < 2; ++nt) {
      const float* p = bp + (size_t)(nt * 16 + lr) * GD + kt * 32 + lh * 8;
      float4 v0 = *(const float4*)p;
      float4 v1 = *(const float4*)(p + 4);
      float s = fracv[nt];
      v0.x*=s; v0.y*=s; v0.z*=s; v0.w*=s;
      v1.x*=s; v1.y*=s; v1.z*=s; v1.w*=s;
      bfr[kt][nt] = pack8(v0, v1);
    }

  const float* up = u + ((size_t)b * TT + (size_t)c * CL) * DM + g * GD;
  float4 ub[2][4][2];
  #pragma unroll
  for (int kt = 0; kt < 2; ++kt)
    #pragma unroll
    for (int m = 0; m < 4; ++m) {
      const float* p = up + (size_t)(m * 16 + lr) * DM + kt * 32 + lh * 8;
      ub[kt][m][0] = *(const float4*)p;
      ub[kt][m][1] = *(const float4*)(p + 4);
    }

  f32x4 acc[4][2];
  #pragma unroll
  for (int m = 0; m < 4; ++m)
    #pragma unroll
    for (int nt = 0; nt < 2; ++nt)
      #pragma unroll
      for (int j = 0; j < 4; ++j) acc[m][nt][j] = 0.f;

  #pragma unroll
  for (int kt = 0; kt < 4; ++kt) {
    short8 af[4];
    #pragma unroll
    for (int m = 0; m < 4; ++m)
      af[m] = pack8(ub[kt & 1][m][0], ub[kt & 1][m][1]);
    if (kt < 2) {
      #pragma unroll
      for (int m = 0; m < 4; ++m) {
        const float* p = up + (size_t)(m * 16 + lr) * DM + (kt + 2) * 32 + lh * 8;
        ub[kt & 1][m][0] = *(const float4*)p;
        ub[kt & 1][m][1] = *(const float4*)(p + 4);
      }
    }
    #pragma unroll
    for (int m = 0; m < 4; ++m)
      #pragma unroll
      for (int nt = 0; nt < 2; ++nt)
        acc[m][nt] = __builtin_amdgcn_mfma_f32_16x16x32_bf16(af[m], bfr[kt][nt], acc[m][nt], 0, 0, 0);
  }

  __shared__ __align__(16) float sBu[CL * 33];            // 8448B
  __shared__ __align__(16) unsigned short sSt[CL * SD];   // 4096B
  #pragma unroll
  for (int m = 0; m < 4; ++m)
    #pragma unroll
    for (int nt = 0; nt < 2; ++nt)
      #pragma unroll
      for (int j = 0; j < 4; ++j) {
        int t = m * 16 + lh * 4 + j;   // C/D: row=(lane>>4)*4+j, col=lane&15
        sBu[t * 33 + (nt * 16 + lr)] = acc[m][nt][j];
      }
  __syncthreads();

  float* carry = (float*)(ws + WS_CARRY);
  if (l < SD) {
    float s = 0.f;
    #pragma unroll
    for (int t = 0; t < CL; ++t) {
      s = fmaf(s, a_scan, sBu[t * 33 + l]);
      sSt[t * SD + l] = f2bf(s);
    }
    carry[((b * NG + g) * NC + c) * SD + l] = s;   // [b][g][c][n]
  }
  __syncthreads();

  unsigned short* stg = (unsigned short*)(ws + WS_STL) + ((size_t)((b * NC + c) * NG + g)) * CL * SD;
  #pragma unroll
  for (int p = 0; p < 4; ++p) {
    int off = (p * 64 + l) * 8;        // 2048 ushorts
    *(short8*)(stg + off) = *(short8*)(sSt + off);
  }

  if (b == 0 && c == 0 && l < SD) {
    float* powA = (float*)(ws + WS_POWA);
    float* powAL = (float*)(ws + WS_PAL);
    float p = 1.f;
    #pragma unroll
    for (int t = 0; t < CL; ++t) {
      p *= a_scan;
      powA[(g * CL + t) * SD + l] = p;
    }
    float aL = p;                       // a^64
    float q = 1.f;
    #pragma unroll
    for (int j = 0; j < CL; ++j) {
      powAL[(g * CL + j) * SD + l] = q; // aL^j
      q *= aL;
    }
  }
}

// ---------------- KB: 2-wave d-split + C GEMM + transposed coalesced y store (R11; g-fastest) ----------------
__global__ __launch_bounds__(128) void kb_y(const float* __restrict__ u,
                                            const float* __restrict__ state0,
                                            const float* __restrict__ C,
                                            const float* __restrict__ Dp,
                                            unsigned char* __restrict__ ws,
                                            float* __restrict__ y,
                                            float* __restrict__ sfin) {
  const int bx = blockIdx.x;
  // DISPATCH REMAP: g fastest -> the 8 blocks writing each 4KB y-row dispatch together.
  const int g = bx & (NG - 1);
  const int c = (bx >> 3) & (NC - 1);
  const int b = bx >> 9;
  const int tid = threadIdx.x;
  const int w = tid >> 6;          // wave 0..1 -> d-half
  const int l = tid & 63;
  const int lr = l & 15, lh = l >> 4;
  const int n = l & 31;

  const float* powA = (const float*)(ws + WS_POWA) + g * CL * SD;
  const float* powAL = (const float*)(ws + WS_PAL) + g * CL * SD;
  const float* carry = (const float*)(ws + WS_CARRY) + (size_t)(b * NG + g) * NC * SD;  // [c][n]
  const unsigned short* stg = (const unsigned short*)(ws + WS_STL) + ((size_t)((b * NC + c) * NG + g)) * CL * SD;

  __shared__ __align__(16) float sY[32 * 132];   // 16896B transpose buffer

  bool need_u;
  {
    float2 dpc = *(const float2*)(Dp + g * GD + l * 2);
    need_u = __ballot((dpc.x != 0.f) || (dpc.y != 0.f)) != 0ULL;
  }

  // --- chunk-entry prefix (per wave, redundant) ---
  float p;
  {
    float a0 = 0.f, a1 = 0.f, a2 = 0.f, a3 = 0.f;
    int cc = 0;
    while (cc + 8 <= c) {
      float ca[8], wt[8];
      #pragma unroll
      for (int e = 0; e < 8; ++e) {
        ca[e] = carry[(cc + e) * SD + n];
        wt[e] = powAL[(c - 1 - cc - e) * SD + n];
      }
      a0 = fmaf(wt[0], ca[0], a0); a1 = fmaf(wt[1], ca[1], a1);
      a2 = fmaf(wt[2], ca[2], a2); a3 = fmaf(wt[3], ca[3], a3);
      a0 = fmaf(wt[4], ca[4], a0); a1 = fmaf(wt[5], ca[5], a1);
      a2 = fmaf(wt[6], ca[6], a2); a3 = fmaf(wt[7], ca[7], a3);
      cc += 8;
    }
    for (; cc < c; ++cc)
      a0 = fmaf(powAL[(c - 1 - cc) * SD + n], carry[cc * SD + n], a0);
    p = fmaf(state0[(b * NG + g) * SD + n], powAL[c * SD + n], (a0 + a1) + (a2 + a3));
  }
  if (w == 0 && c == NC - 1 && l < SD) {
    const float aL = powA[(CL - 1) * SD + l];
    sfin[(b * NG + g) * SD + l] = fmaf(p, aL, carry[(NC - 1) * SD + l]);
  }

  float pr[8];
  #pragma unroll
  for (int e = 0; e < 8; ++e) pr[e] = __shfl(p, lh * 8 + e);

  // --- corrected state fragments (B operand, col = t, k = n) ---
  short8 sf[4];
  #pragma unroll
  for (int tt = 0; tt < 4; ++tt) {
    int t = tt * 16 + lr;
    short8 sl = *(const short8*)(stg + t * SD + lh * 8);
    const float* pw = powA + t * SD + lh * 8;
    float4 pw0 = *(const float4*)pw;
    float4 pw1 = *(const float4*)(pw + 4);
    short8 hh;
    hh[0] = (short)f2bf(bf2f((unsigned short)sl[0]) + pw0.x * pr[0]);
    hh[1] = (short)f2bf(bf2f((unsigned short)sl[1]) + pw0.y * pr[1]);
    hh[2] = (short)f2bf(bf2f((unsigned short)sl[2]) + pw0.z * pr[2]);
    hh[3] = (short)f2bf(bf2f((unsigned short)sl[3]) + pw0.w * pr[3]);
    hh[4] = (short)f2bf(bf2f((unsigned short)sl[4]) + pw1.x * pr[4]);
    hh[5] = (short)f2bf(bf2f((unsigned short)sl[5]) + pw1.y * pr[5]);
    hh[6] = (short)f2bf(bf2f((unsigned short)sl[6]) + pw1.z * pr[6]);
    hh[7] = (short)f2bf(bf2f((unsigned short)sl[7]) + pw1.w * pr[7]);
    sf[tt] = hh;
  }

  // --- GEMM (swapped): D[d][t] = sum_n C[d][n]*s[t][n]; wave w owns d-half w ---
  const float* cp = C + (size_t)g * GD * SD;
  const size_t rowbase = ((size_t)b * TT + (size_t)c * CL) * DM + g * GD;

  short8 cf[4];
  #pragma unroll
  for (int dd = 0; dd < 4; ++dd) {
    int d = (w * 4 + dd) * 16 + lr;
    const float* pp = cp + (size_t)d * SD + lh * 8;
    float4 v0 = *(const float4*)pp;
    float4 v1 = *(const float4*)(pp + 4);
    cf[dd] = pack8(v0, v1);
  }
  f32x4 acc[4][4];
  #pragma unroll
  for (int dd = 0; dd < 4; ++dd)
    #pragma unroll
    for (int tt = 0; tt < 4; ++tt) {
      f32x4 z;
      #pragma unroll
      for (int j = 0; j < 4; ++j) z[j] = 0.f;
      acc[dd][tt] = __builtin_amdgcn_mfma_f32_16x16x32_bf16(cf[dd], sf[tt], z, 0, 0, 0);
    }

  // --- epilogue: LDS transpose (two 32-t halves) -> fully coalesced y stores ---
  const int sd4 = (tid & 31) * 4;
  float4 dpv = *(const float4*)(Dp + g * GD + sd4);

  #pragma unroll
  for (int tp = 0; tp < 2; ++tp) {
    if (tp) __syncthreads();
    #pragma unroll
    for (int dd = 0; dd < 4; ++dd)
      #pragma unroll
      for (int q = 0; q < 2; ++q) {
        int tt = tp * 2 + q;
        int tl = q * 16 + lr;
        int d0 = (w * 4 + dd) * 16 + lh * 4;
        *(float4*)(sY + tl * 132 + d0) = (float4){acc[dd][tt][0], acc[dd][tt][1],
                                                  acc[dd][tt][2], acc[dd][tt][3]};
      }
    __syncthreads();
    #pragma unroll
    for (int r = 0; r < 8; ++r) {
      int tl = r * 4 + (tid >> 5);
      int t = tp * 32 + tl;
      float4 v = *(const float4*)(sY + tl * 132 + sd4);
      size_t off = rowbase + (size_t)t * DM + sd4;
      if (need_u) {
        float4 u4 = *(const float4*)(u + off);
        v.x += dpv.x * u4.x; v.y += dpv.y * u4.y;
        v.z += dpv.z * u4.z; v.w += dpv.w * u4.w;
      }
      *(float4*)(y + off) = v;
    }
  }
}

extern "C" void kernel_launch(void* const* d_in, const int* in_sizes, int n_in,
                              void* d_out, int out_size, void* d_ws, size_t ws_size,
                              hipStream_t stream) {
  const float* u       = (const float*)d_in[0];
  const float* state0  = (const float*)d_in[1];
  const float* A_log   = (const float*)d_in[2];
  const float* B_param = (const float*)d_in[3];
  const float* C       = (const float*)d_in[4];
  const float* Dp      = (const float*)d_in[5];
  const float* dtl     = (const float*)d_in[6];
  float* y = (float*)d_out;
  unsigned char* ws = (unsigned char*)d_ws;
  float* sfin = y + (size_t)BS * TT * DM;

  ka_bu_scan<<<dim3(BS * NG * NC), dim3(64), 0, stream>>>(u, A_log, B_param, dtl, ws);
  kb_y<<<dim3(BS * NG * NC), dim3(128), 0, stream>>>(u, state0, C, Dp, ws, y, sfin);
}